// Round 1
// baseline (239.435 us; speedup 1.0000x reference)
//
#include <hip/hip_runtime.h>
#include <cstdint>

#define DEV static __device__ __forceinline__

typedef float f32x4 __attribute__((ext_vector_type(4)));
typedef short bf16x8 __attribute__((ext_vector_type(8)));   // 8 bf16 in 4 VGPRs (guide §3)

constexpr int Bsz = 16384;
constexpr int Dd  = 1024;   // D
constexpr int DKd = 1024;   // DK

// float -> bf16 bits, round-to-nearest-even
DEV unsigned short f2bf(float f) {
    uint32_t u = __builtin_bit_cast(uint32_t, f);
    u += 0x7FFFu + ((u >> 16) & 1u);
    return (unsigned short)(u >> 16);
}

// async global->LDS, 16 bytes per lane (dest must be linear: base + lane*16)
DEV void async_lds16(const void* g, void* l) {
    __builtin_amdgcn_global_load_lds(
        (const __attribute__((address_space(1))) void*)g,
        (__attribute__((address_space(3))) void*)l,
        16, 0, 0);
}

// ---------------- prep: mixed = mix*x + (1-mix)*x_prev, cast to bf16 ----------------
__global__ void k_mix_bf16(const float4* __restrict__ x, const float4* __restrict__ xp,
                           const float* __restrict__ mixp, unsigned short* __restrict__ out,
                           int n4) {
    const float m = *mixp, m1 = 1.0f - m;
    int i = blockIdx.x * blockDim.x + threadIdx.x;
    const int st = gridDim.x * blockDim.x;
    for (; i < n4; i += st) {
        float4 a = x[i], b = xp[i];
        ushort4 o;
        o.x = f2bf(m * a.x + m1 * b.x);
        o.y = f2bf(m * a.y + m1 * b.y);
        o.z = f2bf(m * a.z + m1 * b.z);
        o.w = f2bf(m * a.w + m1 * b.w);
        reinterpret_cast<ushort4*>(out)[i] = o;
    }
}

// ---------------- prep: f32 -> bf16 cast (weights) ----------------
__global__ void k_cvt_bf16(const float4* __restrict__ in, unsigned short* __restrict__ out,
                           int n4) {
    int i = blockIdx.x * blockDim.x + threadIdx.x;
    const int st = gridDim.x * blockDim.x;
    for (; i < n4; i += st) {
        float4 a = in[i];
        ushort4 o;
        o.x = f2bf(a.x);
        o.y = f2bf(a.y);
        o.z = f2bf(a.z);
        o.w = f2bf(a.w);
        reinterpret_cast<ushort4*>(out)[i] = o;
    }
}

// ---------------- NT GEMM: C[M,N] = A[M,1024] * Bw[N,1024]^T, 128x128 tile, BK=64 ----
// EPI==1: RWKV epilogue (K -> num_new, den_new, rwkv_bf16)
// EPI==0: bias epilogue (out = C + bias)
template <int EPI>
__global__ __launch_bounds__(256)
void k_gemm(const unsigned short* __restrict__ A,   // [M,1024] bf16
            const unsigned short* __restrict__ Bw,  // [N,1024] bf16
            const float* __restrict__ bias,         // bk (EPI=1) or bf (EPI=0)
            const float* __restrict__ num, const float* __restrict__ den,
            const float* __restrict__ bonus, const float* __restrict__ decayp,
            float* __restrict__ o0,                 // num_new / out
            float* __restrict__ o1,                 // den_new
            unsigned short* __restrict__ orw)       // rwkv bf16
{
    __shared__ __align__(16) unsigned short As[128 * 64];
    __shared__ __align__(16) unsigned short Bs[128 * 64];

    const int tid = threadIdx.x;
    const int nwg = gridDim.x;
    // bijective XCD swizzle (nwg % 8 == 0): each XCD gets a contiguous wg chunk
    int wg = ((int)blockIdx.x & 7) * (nwg >> 3) + ((int)blockIdx.x >> 3);
    const int cb = wg & 7;    // N/128 = 8 column blocks
    const int rb = wg >> 3;
    const int row0 = rb * 128;
    const int col0 = cb * 128;

    const int lane = tid & 63;
    const int wid  = tid >> 6;
    const int wr = wid >> 1, wc = wid & 1;   // 2x2 wave grid, 64x64 per wave
    const int l16 = lane & 15, lq = lane >> 4;
    const int xm = l16 & 7;                  // XOR-swizzle mask for ds_read

    f32x4 acc[4][4] = {};

    for (int kt = 0; kt < 1024 / 64; ++kt) {
        const int kbase = kt * 64;
        // stage A tile (128 rows x 64 k) — source pre-swizzled, LDS linear (rule #21)
#pragma unroll
        for (int i = 0; i < 4; ++i) {
            int seg = i * 256 + tid;          // 0..1023 16B-chunks
            int r = seg >> 3;
            int cg = (seg & 7) ^ (r & 7);     // swizzled source column
            async_lds16(A + (row0 + r) * 1024 + kbase + cg * 8, As + seg * 8);
        }
        // stage B tile (128 rows x 64 k)
#pragma unroll
        for (int i = 0; i < 4; ++i) {
            int seg = i * 256 + tid;
            int r = seg >> 3;
            int cg = (seg & 7) ^ (r & 7);
            async_lds16(Bw + (col0 + r) * 1024 + kbase + cg * 8, Bs + seg * 8);
        }
        __syncthreads();   // compiler emits vmcnt(0) drain before barrier

#pragma unroll
        for (int kk = 0; kk < 2; ++kk) {
            bf16x8 af[4], bfr[4];
#pragma unroll
            for (int m = 0; m < 4; ++m) {
                int row = wr * 64 + m * 16 + l16;
                int j = (kk * 4 + lq) ^ xm;   // undo the source swizzle
                af[m] = *reinterpret_cast<const bf16x8*>(As + row * 64 + j * 8);
            }
#pragma unroll
            for (int n = 0; n < 4; ++n) {
                int row = wc * 64 + n * 16 + l16;
                int j = (kk * 4 + lq) ^ xm;
                bfr[n] = *reinterpret_cast<const bf16x8*>(Bs + row * 64 + j * 8);
            }
#pragma unroll
            for (int m = 0; m < 4; ++m)
#pragma unroll
                for (int n = 0; n < 4; ++n)
                    acc[m][n] = __builtin_amdgcn_mfma_f32_16x16x32_bf16(
                        af[m], bfr[n], acc[m][n], 0, 0, 0);
        }
        __syncthreads();
    }

    // ---------------- epilogue ----------------
    float w_decay = 0.0f;
    if constexpr (EPI == 1) w_decay = expf(-expf(*decayp));

    const int baserow = row0 + wr * 64 + lq * 4;   // + m*16 + r
    const int basecol = col0 + wc * 64 + l16;      // + n*16

#pragma unroll
    for (int m = 0; m < 4; ++m) {
#pragma unroll
        for (int n = 0; n < 4; ++n) {
            const int gcol = basecol + n * 16;
#pragma unroll
            for (int r = 0; r < 4; ++r) {
                const int grow = baserow + m * 16 + r;
                const int idx = grow * 1024 + gcol;
                const float v = acc[m][n][r];
                if constexpr (EPI == 1) {
                    const float Kv  = v + bias[gcol];
                    const float nb  = num[idx];
                    const float db  = den[idx];
                    const float ebk = expf(bonus[gcol] + Kv);
                    const float wkv = (nb + ebk * Kv) / (db + ebk);
                    const float sig = 1.0f / (1.0f + expf(-Kv));
                    const float eK  = expf(Kv);
                    o0[idx]  = w_decay * nb + eK * Kv;   // num_new
                    o1[idx]  = w_decay * db + eK;        // den_new
                    orw[idx] = f2bf(sig * wkv);          // rwkv (bf16 for GEMM2)
                } else {
                    o0[idx] = v + bias[gcol];            // out
                }
            }
        }
    }
}

extern "C" void kernel_launch(void* const* d_in, const int* in_sizes, int n_in,
                              void* d_out, int out_size, void* d_ws, size_t ws_size,
                              hipStream_t stream) {
    const float* x     = (const float*)d_in[0];
    const float* xprev = (const float*)d_in[1];
    const float* num   = (const float*)d_in[2];
    const float* den   = (const float*)d_in[3];
    const float* Wk    = (const float*)d_in[4];
    const float* bk    = (const float*)d_in[5];
    const float* mixk  = (const float*)d_in[6];
    const float* Wf    = (const float*)d_in[7];
    const float* bf_   = (const float*)d_in[8];
    const float* bonus = (const float*)d_in[9];
    const float* decay = (const float*)d_in[10];

    float* out    = (float*)d_out;                      // [B, D]
    float* numnew = out + (size_t)Bsz * Dd;             // [B, DK]
    float* dennew = numnew + (size_t)Bsz * DKd;         // [B, DK]

    char* ws = (char*)d_ws;
    unsigned short* mixed = (unsigned short*)ws;                       // 32 MB
    unsigned short* WkB   = (unsigned short*)(ws + (size_t)Bsz * Dd * 2);
    unsigned short* WfB   = WkB + (size_t)DKd * Dd;                    // +2 MB
    unsigned short* rwkv  = WfB + (size_t)Dd * DKd;                    // +2 MB, 32 MB

    k_mix_bf16<<<2048, 256, 0, stream>>>((const float4*)x, (const float4*)xprev,
                                         mixk, mixed, Bsz * Dd / 4);
    k_cvt_bf16<<<512, 256, 0, stream>>>((const float4*)Wk, WkB, DKd * Dd / 4);
    k_cvt_bf16<<<512, 256, 0, stream>>>((const float4*)Wf, WfB, Dd * DKd / 4);

    const int grid = (Bsz / 128) * (DKd / 128);   // 1024 blocks
    k_gemm<1><<<grid, 256, 0, stream>>>(mixed, WkB, bk, num, den, bonus, decay,
                                        numnew, dennew, rwkv);
    k_gemm<0><<<grid, 256, 0, stream>>>(rwkv, WfB, bf_, nullptr, nullptr, nullptr,
                                        nullptr, out, nullptr, nullptr);
}

// Round 2
// 184.064 us; speedup vs baseline: 1.3008x; 1.3008x over previous
//
#include <hip/hip_runtime.h>
#include <cstdint>

#define DEV static __device__ __forceinline__

typedef float f32x4 __attribute__((ext_vector_type(4)));
typedef short bf16x8 __attribute__((ext_vector_type(8)));   // 8 bf16 in 4 VGPRs

constexpr int Bsz = 16384;
constexpr int Dd  = 1024;   // D
constexpr int DKd = 1024;   // DK

// float -> bf16 bits, round-to-nearest-even
DEV unsigned short f2bf(float f) {
    uint32_t u = __builtin_bit_cast(uint32_t, f);
    u += 0x7FFFu + ((u >> 16) & 1u);
    return (unsigned short)(u >> 16);
}

// async global->LDS, 16 bytes per lane (dest must be linear: base + lane*16)
DEV void async_lds16(const void* g, void* l) {
    __builtin_amdgcn_global_load_lds(
        (const __attribute__((address_space(1))) void*)g,
        (__attribute__((address_space(3))) void*)l,
        16, 0, 0);
}

// ---------------- prep: mixed = mix*x + (1-mix)*x_prev, cast to bf16 ----------------
__global__ void k_mix_bf16(const float4* __restrict__ x, const float4* __restrict__ xp,
                           const float* __restrict__ mixp, unsigned short* __restrict__ out,
                           int n4) {
    const float m = *mixp, m1 = 1.0f - m;
    int i = blockIdx.x * blockDim.x + threadIdx.x;
    const int st = gridDim.x * blockDim.x;
    for (; i < n4; i += st) {
        float4 a = x[i], b = xp[i];
        ushort4 o;
        o.x = f2bf(m * a.x + m1 * b.x);
        o.y = f2bf(m * a.y + m1 * b.y);
        o.z = f2bf(m * a.z + m1 * b.z);
        o.w = f2bf(m * a.w + m1 * b.w);
        reinterpret_cast<ushort4*>(out)[i] = o;
    }
}

// ---------------- prep: f32 -> bf16 cast (weights) ----------------
__global__ void k_cvt_bf16(const float4* __restrict__ in, unsigned short* __restrict__ out,
                           int n4) {
    int i = blockIdx.x * blockDim.x + threadIdx.x;
    const int st = gridDim.x * blockDim.x;
    for (; i < n4; i += st) {
        float4 a = in[i];
        ushort4 o;
        o.x = f2bf(a.x);
        o.y = f2bf(a.y);
        o.z = f2bf(a.z);
        o.w = f2bf(a.w);
        reinterpret_cast<ushort4*>(out)[i] = o;
    }
}

// ---- NT GEMM: C[M,N] = A[M,1024] * Bw[N,1024]^T, 256x256 tile, BK=64, 8 waves ----
// 2-phase pipeline: STAGE(next) issued BEFORE compute(cur); one drain/barrier per step.
// EPI==1: RWKV epilogue (K -> num_new, den_new, rwkv_bf16); EPI==0: bias epilogue.
template <int EPI>
__global__ __launch_bounds__(512)
void k_gemm(const unsigned short* __restrict__ A,   // [M,1024] bf16
            const unsigned short* __restrict__ Bw,  // [N,1024] bf16
            const float* __restrict__ bias,         // bk (EPI=1) or bf (EPI=0)
            const float* __restrict__ num, const float* __restrict__ den,
            const float* __restrict__ bonus, const float* __restrict__ decayp,
            float* __restrict__ o0,                 // num_new / out
            float* __restrict__ o1,                 // den_new
            unsigned short* __restrict__ orw)       // rwkv bf16
{
    __shared__ __align__(16) unsigned short As[2][256 * 64];   // 64 KB
    __shared__ __align__(16) unsigned short Bs[2][256 * 64];   // 64 KB

    const int tid = threadIdx.x;
    const int nwg = gridDim.x;                      // 256, %8==0
    int wg = ((int)blockIdx.x & 7) * (nwg >> 3) + ((int)blockIdx.x >> 3);
    const int cb = wg & 3;                          // N/256 = 4 column blocks
    const int rb = wg >> 2;
    const int row0 = rb * 256;
    const int col0 = cb * 256;

    const int lane = tid & 63;
    const int wid  = tid >> 6;                      // 0..7
    const int wr = wid >> 2, wc = wid & 3;          // 2x4 wave grid: 128x64 per wave
    const int l16 = lane & 15, lq = lane >> 4;
    const int xm = l16 & 7;                         // XOR-swizzle mask (ds_read side)

    f32x4 acc[8][4] = {};

    // stage one 256x64 A-tile + B-tile; source pre-swizzled, LDS linear (rule #21)
    auto stage = [&](int buf, int kt) {
        const int kbase = kt * 64;
#pragma unroll
        for (int i = 0; i < 4; ++i) {
            int seg = i * 512 + tid;                // 0..2047 16B-chunks
            int r = seg >> 3;
            int cg = (seg & 7) ^ (r & 7);
            async_lds16(A + (size_t)(row0 + r) * 1024 + kbase + cg * 8,
                        &As[buf][seg * 8]);
        }
#pragma unroll
        for (int i = 0; i < 4; ++i) {
            int seg = i * 512 + tid;
            int r = seg >> 3;
            int cg = (seg & 7) ^ (r & 7);
            async_lds16(Bw + (size_t)(col0 + r) * 1024 + kbase + cg * 8,
                        &Bs[buf][seg * 8]);
        }
    };

    stage(0, 0);
    __syncthreads();          // drains vmcnt(0): buf0 ready

    int cur = 0;
    for (int kt = 0; kt < 16; ++kt) {
        if (kt < 15) stage(cur ^ 1, kt + 1);        // prefetch BEFORE compute
#pragma unroll
        for (int kk = 0; kk < 2; ++kk) {
            bf16x8 af[8], bfr[4];
#pragma unroll
            for (int n = 0; n < 4; ++n) {
                int row = wc * 64 + n * 16 + l16;
                int j = (kk * 4 + lq) ^ xm;         // undo source swizzle
                bfr[n] = *reinterpret_cast<const bf16x8*>(&Bs[cur][row * 64 + j * 8]);
            }
#pragma unroll
            for (int m = 0; m < 8; ++m) {
                int row = wr * 128 + m * 16 + l16;
                int j = (kk * 4 + lq) ^ xm;
                af[m] = *reinterpret_cast<const bf16x8*>(&As[cur][row * 64 + j * 8]);
            }
#pragma unroll
            for (int m = 0; m < 8; ++m)
#pragma unroll
                for (int n = 0; n < 4; ++n)
                    acc[m][n] = __builtin_amdgcn_mfma_f32_16x16x32_bf16(
                        af[m], bfr[n], acc[m][n], 0, 0, 0);
        }
        __syncthreads();      // vmcnt(0)+lgkmcnt(0)+barrier: next buf ready, cur free
        cur ^= 1;
    }

    // ---------------- epilogue ----------------
    // C/D layout: col = lane&15, row = (lane>>4)*4 + reg  (guide §3, m89-verified)
    const int baserow = row0 + wr * 128 + lq * 4;
    const int basecol = col0 + wc * 64 + l16;

    if constexpr (EPI == 1) {
        const float w_decay = __expf(-__expf(*decayp));
        float cbias[4], cebon[4];
#pragma unroll
        for (int n = 0; n < 4; ++n) {
            cbias[n] = bias[basecol + n * 16];
            cebon[n] = __expf(bonus[basecol + n * 16]);
        }
#pragma unroll
        for (int m = 0; m < 8; ++m) {
#pragma unroll
            for (int r = 0; r < 4; ++r) {
                const size_t rowoff = (size_t)(baserow + m * 16 + r) * 1024;
#pragma unroll
                for (int n = 0; n < 4; ++n) {
                    const size_t idx = rowoff + basecol + n * 16;
                    const float Kv  = acc[m][n][r] + cbias[n];
                    const float eK  = __expf(Kv);
                    const float ebk = cebon[n] * eK;       // exp(bonus + K)
                    const float nb  = num[idx];
                    const float db  = den[idx];
                    const float wkv = (nb + ebk * Kv) / (db + ebk);
                    const float sig = eK / (1.0f + eK);    // sigmoid(K)
                    o0[idx]  = w_decay * nb + eK * Kv;     // num_new
                    o1[idx]  = w_decay * db + eK;          // den_new
                    orw[idx] = f2bf(sig * wkv);            // rwkv (bf16 for GEMM2)
                }
            }
        }
    } else {
        float cbias[4];
#pragma unroll
        for (int n = 0; n < 4; ++n) cbias[n] = bias[basecol + n * 16];
#pragma unroll
        for (int m = 0; m < 8; ++m) {
#pragma unroll
            for (int r = 0; r < 4; ++r) {
                const size_t rowoff = (size_t)(baserow + m * 16 + r) * 1024;
#pragma unroll
                for (int n = 0; n < 4; ++n)
                    o0[rowoff + basecol + n * 16] = acc[m][n][r] + cbias[n];
            }
        }
    }
}

extern "C" void kernel_launch(void* const* d_in, const int* in_sizes, int n_in,
                              void* d_out, int out_size, void* d_ws, size_t ws_size,
                              hipStream_t stream) {
    const float* x     = (const float*)d_in[0];
    const float* xprev = (const float*)d_in[1];
    const float* num   = (const float*)d_in[2];
    const float* den   = (const float*)d_in[3];
    const float* Wk    = (const float*)d_in[4];
    const float* bk    = (const float*)d_in[5];
    const float* mixk  = (const float*)d_in[6];
    const float* Wf    = (const float*)d_in[7];
    const float* bf_   = (const float*)d_in[8];
    const float* bonus = (const float*)d_in[9];
    const float* decay = (const float*)d_in[10];

    float* out    = (float*)d_out;                      // [B, D]
    float* numnew = out + (size_t)Bsz * Dd;             // [B, DK]
    float* dennew = numnew + (size_t)Bsz * DKd;         // [B, DK]

    char* ws = (char*)d_ws;
    unsigned short* mixed = (unsigned short*)ws;                       // 32 MB
    unsigned short* WkB   = (unsigned short*)(ws + (size_t)Bsz * Dd * 2);
    unsigned short* WfB   = WkB + (size_t)DKd * Dd;                    // +2 MB
    unsigned short* rwkv  = WfB + (size_t)Dd * DKd;                    // +2 MB

    k_mix_bf16<<<2048, 256, 0, stream>>>((const float4*)x, (const float4*)xprev,
                                         mixk, mixed, Bsz * Dd / 4);
    k_cvt_bf16<<<512, 256, 0, stream>>>((const float4*)Wk, WkB, DKd * Dd / 4);
    k_cvt_bf16<<<512, 256, 0, stream>>>((const float4*)Wf, WfB, Dd * DKd / 4);

    const int grid = (Bsz / 256) * (DKd / 256);   // 256 blocks, 1 per CU
    k_gemm<1><<<grid, 512, 0, stream>>>(mixed, WkB, bk, num, den, bonus, decay,
                                        numnew, dennew, rwkv);
    k_gemm<0><<<grid, 512, 0, stream>>>(rwkv, WfB, bf_, nullptr, nullptr, nullptr,
                                        nullptr, out, nullptr, nullptr);
}